// Round 5
// baseline (254.550 us; speedup 1.0000x reference)
//
#include <hip/hip_runtime.h>

#define N_NODES 50000
#define E_EDGES 600000
#define D_IN 128
#define O_OUT 128
#define R_REL 8
#define B_BAS 4
#define KTOT 1152                 // 8 relations * 128 + self-loop 128
#define NSEG (N_NODES * R_REL)    // 400000 (dst-major: seg = dst*8 + rel)
#define NB1 782                   // ceil(NSEG/512)
#define BM 64                     // nodes per block
#define NBLK 782                  // ceil(N_NODES/64)

typedef __attribute__((ext_vector_type(8))) short bf16x8;
typedef __attribute__((ext_vector_type(4))) float f32x4;

static __device__ __forceinline__ unsigned short f2bf(float f) {
    unsigned int u = __float_as_uint(f);
    unsigned int r = (u + 0x7fffu + ((u >> 16) & 1u)) >> 16;
    return (unsigned short)r;
}

// Wt2[o][k] bf16, k = r*128 + d:  r<8 -> W_r[d,o] = sum_b coeffs[r,b]*basis_v[b,d,o]
//                                 r==8 -> w_loop[d,o]
__global__ void build_wt2_kernel(const float* __restrict__ basis_v,
                                 const float* __restrict__ coeffs,
                                 const float* __restrict__ w_loop,
                                 unsigned short* __restrict__ Wt2) {
    int i = blockIdx.x * 256 + threadIdx.x;  // over 128*1152 = 147456
    int o = i / KTOT, j = i - o * KTOT;
    int r = j >> 7, d = j & 127;
    float v;
    if (r < R_REL) {
        v = coeffs[r * B_BAS + 0] * basis_v[(0 * D_IN + d) * O_OUT + o]
          + coeffs[r * B_BAS + 1] * basis_v[(1 * D_IN + d) * O_OUT + o]
          + coeffs[r * B_BAS + 2] * basis_v[(2 * D_IN + d) * O_OUT + o]
          + coeffs[r * B_BAS + 3] * basis_v[(3 * D_IN + d) * O_OUT + o];
    } else {
        v = w_loop[d * O_OUT + o];
    }
    Wt2[i] = f2bf(v);
}

// Per-(dst,rel) segment counts (int)
__global__ void deg_kernel(const int* __restrict__ dst, const int* __restrict__ rel,
                           int* __restrict__ deg) {
    int e = blockIdx.x * 256 + threadIdx.x;
    if (e >= E_EDGES) return;
    atomicAdd(&deg[dst[e] * R_REL + rel[e]], 1);
}

__global__ __launch_bounds__(512) void scan1_kernel(const int* __restrict__ cnt,
                                                    int* __restrict__ exoff,
                                                    int* __restrict__ bsum) {
    __shared__ int s[512];
    int t = threadIdx.x, i = blockIdx.x * 512 + t;
    int c = (i < NSEG) ? cnt[i] : 0;
    s[t] = c;
    __syncthreads();
    #pragma unroll
    for (int off = 1; off < 512; off <<= 1) {
        int add = (t >= off) ? s[t - off] : 0;
        __syncthreads();
        s[t] += add;
        __syncthreads();
    }
    if (i < NSEG) exoff[i] = s[t] - c;
    if (t == 511) bsum[blockIdx.x] = s[511];
}

__global__ __launch_bounds__(1024) void scan2_kernel(const int* __restrict__ bsum,
                                                     int* __restrict__ bbase) {
    __shared__ int s[1024];
    int t = threadIdx.x;
    int c = (t < NB1) ? bsum[t] : 0;
    s[t] = c;
    __syncthreads();
    #pragma unroll
    for (int off = 1; off < 1024; off <<= 1) {
        int add = (t >= off) ? s[t - off] : 0;
        __syncthreads();
        s[t] += add;
        __syncthreads();
    }
    if (t < NB1) bbase[t] = s[t] - c;
}

__global__ __launch_bounds__(512) void scan3_kernel(const int* __restrict__ exoff,
                                                    const int* __restrict__ bbase,
                                                    int* __restrict__ offs,
                                                    int* __restrict__ cursor) {
    int i = blockIdx.x * 512 + threadIdx.x;
    if (i >= NSEG) return;
    int v = exoff[i] + bbase[i >> 9];
    offs[i] = v;
    cursor[i] = v;
}

__global__ void fill_kernel(const int* __restrict__ src, const int* __restrict__ dst,
                            const int* __restrict__ rel, int* __restrict__ cursor,
                            int* __restrict__ esrc) {
    int e = blockIdx.x * 256 + threadIdx.x;
    if (e >= E_EDGES) return;
    int pos = atomicAdd(&cursor[dst[e] * R_REL + rel[e]], 1);
    esrc[pos] = src[e];
}

// Fused gather-aggregate + GEMM:
// out[64-node tile] = relu( Ahat @ Wstack + bias ),
// Ahat chunk r (128 k-cols) built on the fly in LDS from CSR segment (node, r).
__global__ __launch_bounds__(256) void fgemm_kernel(const float* __restrict__ x,
                                                    const unsigned short* __restrict__ Wt2,
                                                    const int* __restrict__ offs,
                                                    const int* __restrict__ cnt,
                                                    const int* __restrict__ esrc,
                                                    const float* __restrict__ bias,
                                                    float* __restrict__ out) {
    __shared__ short As[BM * 136];    // 64 rows x 128 k, stride 136 (17.4 KB)
    __shared__ short Bs[128 * 136];   // 128 out-cols x 128 k, stride 136 (34.8 KB)
    const int node0 = blockIdx.x * BM;
    const int t = threadIdx.x;
    const int w = t >> 6, l = t & 63;
    const int lr = l & 15, lg = l >> 4;   // frag row/col (0..15), k-group (0..3)

    f32x4 acc[4][2] = {};

    for (int r = 0; r < 9; ++r) {
        // stage B chunk: Bs[o][d] = Wt2[o*1152 + r*128 + d]  (L2-resident source)
        #pragma unroll
        for (int i = 0; i < 8; ++i) {
            int flat = i * 256 + t;            // 2048 chunks of 8 bf16
            int o = flat >> 4, d16 = flat & 15;
            int4 v = *(const int4*)&Wt2[(size_t)o * KTOT + r * 128 + d16 * 8];
            *(int4*)&Bs[o * 136 + d16 * 8] = v;
        }
        // aggregate A chunk: one 16-lane group per node (32 B/lane), 4 rounds
        #pragma unroll
        for (int rd = 0; rd < 4; ++rd) {
            int ni = w * 16 + rd * 4 + lg;     // 0..63
            int node = node0 + ni;
            float4 a0 = make_float4(0.f, 0.f, 0.f, 0.f);
            float4 a1 = make_float4(0.f, 0.f, 0.f, 0.f);
            if (node < N_NODES) {
                if (r < R_REL) {
                    int seg = node * R_REL + r;
                    int beg = offs[seg], n = cnt[seg];
                    for (int k = 0; k < n; ++k) {
                        const float4* xr = (const float4*)&x[(size_t)esrc[beg + k] * D_IN + lr * 8];
                        float4 v0 = xr[0], v1 = xr[1];
                        a0.x += v0.x; a0.y += v0.y; a0.z += v0.z; a0.w += v0.w;
                        a1.x += v1.x; a1.y += v1.y; a1.z += v1.z; a1.w += v1.w;
                    }
                    if (n > 0) {
                        float inv = 1.0f / (float)n;
                        a0.x *= inv; a0.y *= inv; a0.z *= inv; a0.w *= inv;
                        a1.x *= inv; a1.y *= inv; a1.z *= inv; a1.w *= inv;
                    }
                } else {  // self-loop chunk: raw x row
                    const float4* xr = (const float4*)&x[(size_t)node * D_IN + lr * 8];
                    a0 = xr[0]; a1 = xr[1];
                }
            }
            ushort4 o0, o1;
            o0.x = f2bf(a0.x); o0.y = f2bf(a0.y); o0.z = f2bf(a0.z); o0.w = f2bf(a0.w);
            o1.x = f2bf(a1.x); o1.y = f2bf(a1.y); o1.z = f2bf(a1.z); o1.w = f2bf(a1.w);
            *(ushort4*)&As[ni * 136 + lr * 8] = o0;
            *(ushort4*)&As[ni * 136 + lr * 8 + 4] = o1;
        }
        __syncthreads();
        // MFMA: 4 k-steps of 32; wave w owns cols [w*32, w*32+32)
        #pragma unroll
        for (int ks = 0; ks < 4; ++ks) {
            int kb = ks * 32 + lg * 8;
            bf16x8 af[4];
            #pragma unroll
            for (int mf = 0; mf < 4; ++mf)
                af[mf] = *(const bf16x8*)&As[(mf * 16 + lr) * 136 + kb];
            #pragma unroll
            for (int jn = 0; jn < 2; ++jn) {
                bf16x8 bfr = *(const bf16x8*)&Bs[(w * 32 + jn * 16 + lr) * 136 + kb];
                #pragma unroll
                for (int mf = 0; mf < 4; ++mf)
                    acc[mf][jn] = __builtin_amdgcn_mfma_f32_16x16x32_bf16(af[mf], bfr, acc[mf][jn], 0, 0, 0);
            }
        }
        __syncthreads();
    }

    // epilogue: C/D layout col=lane&15, row=(lane>>4)*4+i  [m89-verified]
    #pragma unroll
    for (int jn = 0; jn < 2; ++jn) {
        int col = w * 32 + jn * 16 + lr;
        float bv = bias[col];
        #pragma unroll
        for (int mf = 0; mf < 4; ++mf) {
            #pragma unroll
            for (int i2 = 0; i2 < 4; ++i2) {
                int row = node0 + mf * 16 + lg * 4 + i2;
                if (row < N_NODES)
                    out[(size_t)row * O_OUT + col] = fmaxf(acc[mf][jn][i2] + bv, 0.f);
            }
        }
    }
}

extern "C" void kernel_launch(void* const* d_in, const int* in_sizes, int n_in,
                              void* d_out, int out_size, void* d_ws, size_t ws_size,
                              hipStream_t stream) {
    (void)in_sizes; (void)n_in; (void)out_size; (void)ws_size;
    const float* x       = (const float*)d_in[0];
    const float* basis_v = (const float*)d_in[1];
    const float* coeffs  = (const float*)d_in[2];
    const float* w_loop  = (const float*)d_in[3];
    const float* bias_p  = (const float*)d_in[4];
    const int*   src     = (const int*)d_in[5];
    const int*   dst     = (const int*)d_in[6];
    const int*   rel     = (const int*)d_in[7];
    float* out = (float*)d_out;

    char* ws = (char*)d_ws;
    unsigned short* Wt2    = (unsigned short*)(ws);            //   294,912 B
    int*            deg    = (int*)(ws + 294912);              // 1,600,000 B (= cnt)
    int*            offs   = (int*)(ws + 1894912);             // 1,600,000 B
    int*            cursor = (int*)(ws + 3494912);             // 1,600,000 B
    int*            exoff  = (int*)(ws + 5094912);             // 1,600,000 B
    int*            bsum   = (int*)(ws + 6694912);             //     4,096 B
    int*            bbase  = (int*)(ws + 6699008);             //     4,096 B
    int*            esrc   = (int*)(ws + 6703104);             // 2,400,000 B

    hipMemsetAsync(deg, 0, (size_t)NSEG * sizeof(int), stream);

    build_wt2_kernel<<<(O_OUT * KTOT) / 256, 256, 0, stream>>>(basis_v, coeffs, w_loop, Wt2);
    deg_kernel<<<(E_EDGES + 255) / 256, 256, 0, stream>>>(dst, rel, deg);
    scan1_kernel<<<NB1, 512, 0, stream>>>(deg, exoff, bsum);
    scan2_kernel<<<1, 1024, 0, stream>>>(bsum, bbase);
    scan3_kernel<<<NB1, 512, 0, stream>>>(exoff, bbase, offs, cursor);
    fill_kernel<<<(E_EDGES + 255) / 256, 256, 0, stream>>>(src, dst, rel, cursor, esrc);
    fgemm_kernel<<<NBLK, 256, 0, stream>>>(x, Wt2, offs, deg, esrc, bias_p, out);
}

// Round 6
// 184.716 us; speedup vs baseline: 1.3781x; 1.3781x over previous
//
#include <hip/hip_runtime.h>

#define N_NODES 50000
#define E_EDGES 600000
#define D_IN 128
#define O_OUT 128
#define R_REL 8
#define B_BAS 4
#define KTOT 1152                 // 8 relations * 128 + self-loop 128
#define NSEG (N_NODES * R_REL)    // 400000 (dst-major: seg = dst*8 + rel)
#define NB1 782                   // ceil(NSEG/512)
#define PLANE (N_NODES * D_IN)    // elems per relation plane of Ahat
#define BM 64                     // nodes per gemm block

typedef __attribute__((ext_vector_type(8))) short bf16x8;
typedef __attribute__((ext_vector_type(4))) float f32x4;

static __device__ __forceinline__ unsigned short f2bf(float f) {
    unsigned int u = __float_as_uint(f);
    unsigned int r = (u + 0x7fffu + ((u >> 16) & 1u)) >> 16;
    return (unsigned short)r;
}
static __device__ __forceinline__ float bf2f(unsigned short b) {
    return __uint_as_float(((unsigned int)b) << 16);
}

// x fp32 [N,128] -> xb bf16
__global__ void convert_x_kernel(const float* __restrict__ x, unsigned short* __restrict__ xb) {
    int i = (blockIdx.x * 256 + threadIdx.x) * 4;
    float4 v = *(const float4*)&x[i];
    ushort4 o;
    o.x = f2bf(v.x); o.y = f2bf(v.y); o.z = f2bf(v.z); o.w = f2bf(v.w);
    *(ushort4*)&xb[i] = o;
}

// Wt2[o][k] bf16, k = r*128 + d:  r<8 -> W_r[d,o];  r==8 -> w_loop[d,o]
__global__ void build_wt2_kernel(const float* __restrict__ basis_v,
                                 const float* __restrict__ coeffs,
                                 const float* __restrict__ w_loop,
                                 unsigned short* __restrict__ Wt2) {
    int i = blockIdx.x * 256 + threadIdx.x;  // over 128*1152
    int o = i / KTOT, j = i - o * KTOT;
    int r = j >> 7, d = j & 127;
    float v;
    if (r < R_REL) {
        v = coeffs[r * B_BAS + 0] * basis_v[(0 * D_IN + d) * O_OUT + o]
          + coeffs[r * B_BAS + 1] * basis_v[(1 * D_IN + d) * O_OUT + o]
          + coeffs[r * B_BAS + 2] * basis_v[(2 * D_IN + d) * O_OUT + o]
          + coeffs[r * B_BAS + 3] * basis_v[(3 * D_IN + d) * O_OUT + o];
    } else {
        v = w_loop[d * O_OUT + o];
    }
    Wt2[i] = f2bf(v);
}

// Per-(dst,rel) segment counts
__global__ void deg_kernel(const int* __restrict__ dst, const int* __restrict__ rel,
                           int* __restrict__ deg) {
    int e = blockIdx.x * 256 + threadIdx.x;
    if (e >= E_EDGES) return;
    atomicAdd(&deg[dst[e] * R_REL + rel[e]], 1);
}

__global__ __launch_bounds__(512) void scan1_kernel(const int* __restrict__ cnt,
                                                    int* __restrict__ exoff,
                                                    int* __restrict__ bsum) {
    __shared__ int s[512];
    int t = threadIdx.x, i = blockIdx.x * 512 + t;
    int c = (i < NSEG) ? cnt[i] : 0;
    s[t] = c;
    __syncthreads();
    #pragma unroll
    for (int off = 1; off < 512; off <<= 1) {
        int add = (t >= off) ? s[t - off] : 0;
        __syncthreads();
        s[t] += add;
        __syncthreads();
    }
    if (i < NSEG) exoff[i] = s[t] - c;
    if (t == 511) bsum[blockIdx.x] = s[511];
}

__global__ __launch_bounds__(1024) void scan2_kernel(const int* __restrict__ bsum,
                                                     int* __restrict__ bbase) {
    __shared__ int s[1024];
    int t = threadIdx.x;
    int c = (t < NB1) ? bsum[t] : 0;
    s[t] = c;
    __syncthreads();
    #pragma unroll
    for (int off = 1; off < 1024; off <<= 1) {
        int add = (t >= off) ? s[t - off] : 0;
        __syncthreads();
        s[t] += add;
        __syncthreads();
    }
    if (t < NB1) bbase[t] = s[t] - c;
}

__global__ __launch_bounds__(512) void scan3_kernel(const int* __restrict__ exoff,
                                                    const int* __restrict__ bbase,
                                                    int* __restrict__ offs,
                                                    int* __restrict__ cursor) {
    int i = blockIdx.x * 512 + threadIdx.x;
    if (i >= NSEG) return;
    int v = exoff[i] + bbase[i >> 9];
    offs[i] = v;
    cursor[i] = v;
}

__global__ void fill_kernel(const int* __restrict__ src, const int* __restrict__ dst,
                            const int* __restrict__ rel, int* __restrict__ cursor,
                            int* __restrict__ esrc) {
    int e = blockIdx.x * 256 + threadIdx.x;
    if (e >= E_EDGES) return;
    int pos = atomicAdd(&cursor[dst[e] * R_REL + rel[e]], 1);
    esrc[pos] = src[e];
}

// segagg: one 16-lane group per (dst,rel) segment. No LDS, no barriers, max occupancy.
// Ahat[r][node][128] bf16 = inv_deg * sum over segment of xb[src]; zeros if empty.
__global__ __launch_bounds__(256) void segagg_kernel(const unsigned short* __restrict__ xb,
                                                     const int* __restrict__ offs,
                                                     const int* __restrict__ cnt,
                                                     const int* __restrict__ esrc,
                                                     unsigned short* __restrict__ Ahat) {
    int sidx = blockIdx.x * 16 + (threadIdx.x >> 4);  // grid exact: NSEG/16
    int l = threadIdx.x & 15;
    int node = sidx >> 3, r = sidx & 7;
    int beg = offs[sidx], n = cnt[sidx];
    float a[8] = {0.f, 0.f, 0.f, 0.f, 0.f, 0.f, 0.f, 0.f};
    for (int k = 0; k < n; ++k) {
        int s = esrc[beg + k];
        bf16x8 v = *(const bf16x8*)&xb[(size_t)s * D_IN + l * 8];
        #pragma unroll
        for (int j = 0; j < 8; ++j) a[j] += bf2f((unsigned short)v[j]);
    }
    float inv = (n > 0) ? (1.0f / (float)n) : 0.0f;
    ushort4 o0, o1;
    o0.x = f2bf(a[0] * inv); o0.y = f2bf(a[1] * inv);
    o0.z = f2bf(a[2] * inv); o0.w = f2bf(a[3] * inv);
    o1.x = f2bf(a[4] * inv); o1.y = f2bf(a[5] * inv);
    o1.z = f2bf(a[6] * inv); o1.w = f2bf(a[7] * inv);
    size_t base = (size_t)r * PLANE + (size_t)node * D_IN + l * 8;
    *(ushort4*)&Ahat[base] = o0;
    *(ushort4*)&Ahat[base + 4] = o1;
}

// gemm2: out[64 nodes x 128] = relu([Ahat planes | xb] @ Wstack + bias).
// Every A-chunk is a contiguous 32 KB stream; B chunks are L2-resident.
__global__ __launch_bounds__(256) void gemm2_kernel(const unsigned short* __restrict__ Ahat,
                                                    const unsigned short* __restrict__ xb,
                                                    const unsigned short* __restrict__ Wt2,
                                                    const float* __restrict__ bias,
                                                    float* __restrict__ out) {
    __shared__ short As[BM * 136];    // 64 rows x 128 k (17.4 KB)
    __shared__ short Bs[128 * 136];   // 128 out-cols x 128 k (34.8 KB)
    const int node0 = blockIdx.x * BM;
    const int t = threadIdx.x;
    const int w = t >> 6, l = t & 63;
    const int lr = l & 15, lg = l >> 4;

    f32x4 acc[4][2] = {};

    for (int r = 0; r < 9; ++r) {
        const unsigned short* Asrc = (r < R_REL)
            ? (Ahat + (size_t)r * PLANE + (size_t)node0 * D_IN)
            : (xb + (size_t)node0 * D_IN);
        // stage A chunk: 1024 x 16B, fully contiguous
        #pragma unroll
        for (int i = 0; i < 4; ++i) {
            int flat = i * 256 + t;
            int rw = flat >> 4, c16 = flat & 15;
            int4 v = make_int4(0, 0, 0, 0);
            if (node0 + rw < N_NODES) v = *(const int4*)&Asrc[(size_t)flat * 8];
            *(int4*)&As[rw * 136 + c16 * 8] = v;
        }
        // stage B chunk: Bs[o][d] = Wt2[o*1152 + r*128 + d]
        #pragma unroll
        for (int i = 0; i < 8; ++i) {
            int flat = i * 256 + t;
            int o = flat >> 4, d16 = flat & 15;
            int4 v = *(const int4*)&Wt2[(size_t)o * KTOT + r * 128 + d16 * 8];
            *(int4*)&Bs[o * 136 + d16 * 8] = v;
        }
        __syncthreads();
        #pragma unroll
        for (int ks = 0; ks < 4; ++ks) {
            int kb = ks * 32 + lg * 8;
            bf16x8 af[4];
            #pragma unroll
            for (int mf = 0; mf < 4; ++mf)
                af[mf] = *(const bf16x8*)&As[(mf * 16 + lr) * 136 + kb];
            #pragma unroll
            for (int jn = 0; jn < 2; ++jn) {
                bf16x8 bfr = *(const bf16x8*)&Bs[(w * 32 + jn * 16 + lr) * 136 + kb];
                #pragma unroll
                for (int mf = 0; mf < 4; ++mf)
                    acc[mf][jn] = __builtin_amdgcn_mfma_f32_16x16x32_bf16(af[mf], bfr, acc[mf][jn], 0, 0, 0);
            }
        }
        __syncthreads();
    }

    // epilogue: C/D layout col=lane&15, row=(lane>>4)*4+i  [m89-verified]
    #pragma unroll
    for (int jn = 0; jn < 2; ++jn) {
        int col = w * 32 + jn * 16 + lr;
        float bv = bias[col];
        #pragma unroll
        for (int mf = 0; mf < 4; ++mf) {
            #pragma unroll
            for (int i2 = 0; i2 < 4; ++i2) {
                int row = node0 + mf * 16 + lg * 4 + i2;
                if (row < N_NODES)
                    out[(size_t)row * O_OUT + col] = fmaxf(acc[mf][jn][i2] + bv, 0.f);
            }
        }
    }
}

extern "C" void kernel_launch(void* const* d_in, const int* in_sizes, int n_in,
                              void* d_out, int out_size, void* d_ws, size_t ws_size,
                              hipStream_t stream) {
    (void)in_sizes; (void)n_in; (void)out_size; (void)ws_size;
    const float* x       = (const float*)d_in[0];
    const float* basis_v = (const float*)d_in[1];
    const float* coeffs  = (const float*)d_in[2];
    const float* w_loop  = (const float*)d_in[3];
    const float* bias_p  = (const float*)d_in[4];
    const int*   src     = (const int*)d_in[5];
    const int*   dst     = (const int*)d_in[6];
    const int*   rel     = (const int*)d_in[7];
    float* out = (float*)d_out;

    char* ws = (char*)d_ws;
    unsigned short* Wt2    = (unsigned short*)(ws);             //     294,912 B
    unsigned short* xb     = (unsigned short*)(ws + 294912);    //  12,800,000 B
    int*            deg    = (int*)(ws + 13094912);             //   1,600,000 B (= cnt)
    int*            exoff  = (int*)(ws + 14694912);             //   1,600,000 B
    int*            offs   = (int*)(ws + 16294912);             //   1,600,000 B
    int*            cursor = (int*)(ws + 17894912);             //   1,600,000 B
    int*            bsum   = (int*)(ws + 19494912);             //       4,096 B
    int*            bbase  = (int*)(ws + 19499008);             //       4,096 B
    int*            esrc   = (int*)(ws + 19503104);             //   2,400,000 B
    unsigned short* Ahat   = (unsigned short*)(ws + 21903104);  // 102,400,000 B

    hipMemsetAsync(deg, 0, (size_t)NSEG * sizeof(int), stream);

    convert_x_kernel<<<N_NODES * D_IN / 1024, 256, 0, stream>>>(x, xb);
    build_wt2_kernel<<<(O_OUT * KTOT) / 256, 256, 0, stream>>>(basis_v, coeffs, w_loop, Wt2);
    deg_kernel<<<(E_EDGES + 255) / 256, 256, 0, stream>>>(dst, rel, deg);
    scan1_kernel<<<NB1, 512, 0, stream>>>(deg, exoff, bsum);
    scan2_kernel<<<1, 1024, 0, stream>>>(bsum, bbase);
    scan3_kernel<<<NB1, 512, 0, stream>>>(exoff, bbase, offs, cursor);
    fill_kernel<<<(E_EDGES + 255) / 256, 256, 0, stream>>>(src, dst, rel, cursor, esrc);
    segagg_kernel<<<NSEG / 16, 256, 0, stream>>>(xb, offs, deg, esrc, Ahat);
    gemm2_kernel<<<(N_NODES + BM - 1) / BM, 256, 0, stream>>>(Ahat, xb, Wt2, bias_p, out);
}

// Round 7
// 170.422 us; speedup vs baseline: 1.4936x; 1.0839x over previous
//
#include <hip/hip_runtime.h>

#define N_NODES 50000
#define E_EDGES 600000
#define D_IN 128
#define O_OUT 128
#define R_REL 8
#define B_BAS 4
#define KTOT 640                  // 4 basis * 128 + self-loop 128
#define NSEG (N_NODES * R_REL)    // per-(dst,rel) degree table
#define NB1 98                    // ceil(50000/512) blocks for per-dst scan
#define YSTRIDE 512               // y row: 4 basis * 128
#define BM 64                     // nodes per gemm block

typedef __attribute__((ext_vector_type(8))) short bf16x8;
typedef __attribute__((ext_vector_type(4))) float f32x4;

static __device__ __forceinline__ unsigned short f2bf(float f) {
    unsigned int u = __float_as_uint(f);
    unsigned int r = (u + 0x7fffu + ((u >> 16) & 1u)) >> 16;
    return (unsigned short)r;
}
static __device__ __forceinline__ float bf2f(unsigned short b) {
    return __uint_as_float(((unsigned int)b) << 16);
}

// x fp32 [N,128] -> xb bf16
__global__ void convert_x_kernel(const float* __restrict__ x, unsigned short* __restrict__ xb) {
    int i = (blockIdx.x * 256 + threadIdx.x) * 4;
    float4 v = *(const float4*)&x[i];
    ushort4 o;
    o.x = f2bf(v.x); o.y = f2bf(v.y); o.z = f2bf(v.z); o.w = f2bf(v.w);
    *(ushort4*)&xb[i] = o;
}

// Wt2[o][k] bf16, k = b*128+d (b<4): V_b[d,o];  k = 512+d: w_loop[d,o]. Coeff-free.
__global__ void build_wt2_kernel(const float* __restrict__ basis_v,
                                 const float* __restrict__ w_loop,
                                 unsigned short* __restrict__ Wt2) {
    int i = blockIdx.x * 256 + threadIdx.x;  // over 128*640 = 81920
    int o = i / KTOT, j = i - o * KTOT;
    int b = j >> 7, d = j & 127;
    float v = (b < B_BAS) ? basis_v[((size_t)b * D_IN + d) * O_OUT + o]
                          : w_loop[d * O_OUT + o];
    Wt2[i] = f2bf(v);
}

// Per-(dst,rel) segment counts
__global__ void deg_kernel(const int* __restrict__ dst, const int* __restrict__ rel,
                           int* __restrict__ deg) {
    int e = blockIdx.x * 256 + threadIdx.x;
    if (e >= E_EDGES) return;
    atomicAdd(&deg[dst[e] * R_REL + rel[e]], 1);
}

// Per-dst total count + per-block scan; also emits invf[dst*8+r] = 1/max(deg,1)
__global__ __launch_bounds__(512) void scan1_kernel(const int* __restrict__ deg,
                                                    int* __restrict__ cntd,
                                                    float* __restrict__ invf,
                                                    int* __restrict__ exoff,
                                                    int* __restrict__ bsum) {
    __shared__ int s[512];
    int t = threadIdx.x, i = blockIdx.x * 512 + t;
    int c = 0;
    if (i < N_NODES) {
        #pragma unroll
        for (int r = 0; r < R_REL; ++r) {
            int dg = deg[i * R_REL + r];
            c += dg;
            invf[i * R_REL + r] = 1.0f / (float)max(dg, 1);
        }
        cntd[i] = c;
    }
    s[t] = c;
    __syncthreads();
    #pragma unroll
    for (int off = 1; off < 512; off <<= 1) {
        int add = (t >= off) ? s[t - off] : 0;
        __syncthreads();
        s[t] += add;
        __syncthreads();
    }
    if (i < N_NODES) exoff[i] = s[t] - c;
    if (t == 511) bsum[blockIdx.x] = s[511];
}

__global__ __launch_bounds__(128) void scan2_kernel(const int* __restrict__ bsum,
                                                    int* __restrict__ bbase) {
    __shared__ int s[128];
    int t = threadIdx.x;
    int c = (t < NB1) ? bsum[t] : 0;
    s[t] = c;
    __syncthreads();
    #pragma unroll
    for (int off = 1; off < 128; off <<= 1) {
        int add = (t >= off) ? s[t - off] : 0;
        __syncthreads();
        s[t] += add;
        __syncthreads();
    }
    if (t < NB1) bbase[t] = s[t] - c;
}

__global__ __launch_bounds__(512) void scan3_kernel(const int* __restrict__ exoff,
                                                    const int* __restrict__ bbase,
                                                    int* __restrict__ offs,
                                                    int* __restrict__ cursor) {
    int i = blockIdx.x * 512 + threadIdx.x;
    if (i >= N_NODES) return;
    int v = exoff[i] + bbase[i >> 9];
    offs[i] = v;
    cursor[i] = v;
}

// Bucket edges per dst; payload packs (rel<<16 | src)  (src < 65536, rel < 8)
__global__ void fill_kernel(const int* __restrict__ src, const int* __restrict__ dst,
                            const int* __restrict__ rel, int* __restrict__ cursor,
                            unsigned* __restrict__ epack) {
    int e = blockIdx.x * 256 + threadIdx.x;
    if (e >= E_EDGES) return;
    int pos = atomicAdd(&cursor[dst[e]], 1);
    epack[pos] = (unsigned)src[e] | ((unsigned)rel[e] << 16);
}

// segagg: one 16-lane group per dst node. y[d][b*128+..] = sum_edges c[rel,b]*inv*x_src
__global__ __launch_bounds__(256) void segagg_kernel(const unsigned short* __restrict__ xb,
                                                     const int* __restrict__ offs,
                                                     const int* __restrict__ cntd,
                                                     const float* __restrict__ invf,
                                                     const unsigned* __restrict__ epack,
                                                     const float* __restrict__ coeffs,
                                                     unsigned short* __restrict__ y) {
    int d = blockIdx.x * 16 + (threadIdx.x >> 4);  // grid exact: 50000/16
    int l = threadIdx.x & 15;
    int beg = offs[d], n = cntd[d];
    float a0[8] = {}, a1[8] = {}, a2[8] = {}, a3[8] = {};
    for (int k = 0; k < n; ++k) {
        unsigned p = epack[beg + k];
        int s = p & 0xffffu, r = p >> 16;
        float invw = invf[d * R_REL + r];
        float c0 = coeffs[r * B_BAS + 0] * invw;
        float c1 = coeffs[r * B_BAS + 1] * invw;
        float c2 = coeffs[r * B_BAS + 2] * invw;
        float c3 = coeffs[r * B_BAS + 3] * invw;
        bf16x8 v = *(const bf16x8*)&xb[(size_t)s * D_IN + l * 8];
        #pragma unroll
        for (int j = 0; j < 8; ++j) {
            float xv = bf2f((unsigned short)v[j]);
            a0[j] += c0 * xv; a1[j] += c1 * xv;
            a2[j] += c2 * xv; a3[j] += c3 * xv;
        }
    }
    size_t base = (size_t)d * YSTRIDE + l * 8;
    #pragma unroll
    for (int b = 0; b < 4; ++b) {
        const float* ab = (b == 0) ? a0 : (b == 1) ? a1 : (b == 2) ? a2 : a3;
        ushort4 o0, o1;
        o0.x = f2bf(ab[0]); o0.y = f2bf(ab[1]); o0.z = f2bf(ab[2]); o0.w = f2bf(ab[3]);
        o1.x = f2bf(ab[4]); o1.y = f2bf(ab[5]); o1.z = f2bf(ab[6]); o1.w = f2bf(ab[7]);
        *(ushort4*)&y[base + b * 128] = o0;
        *(ushort4*)&y[base + b * 128 + 4] = o1;
    }
}

// gemm2: out[64 nodes x 128] = relu([y | xb] @ [Vstack; w_loop] + bias), K=640
__global__ __launch_bounds__(256) void gemm2_kernel(const unsigned short* __restrict__ y,
                                                    const unsigned short* __restrict__ xb,
                                                    const unsigned short* __restrict__ Wt2,
                                                    const float* __restrict__ bias,
                                                    float* __restrict__ out) {
    __shared__ short As[BM * 136];    // 64 rows x 128 k (17.4 KB)
    __shared__ short Bs[128 * 136];   // 128 out-cols x 128 k (34.8 KB)
    const int node0 = blockIdx.x * BM;
    const int t = threadIdx.x;
    const int w = t >> 6, l = t & 63;
    const int lr = l & 15, lg = l >> 4;

    f32x4 acc[4][2] = {};

    for (int r = 0; r < 5; ++r) {
        const unsigned short* Asrc;
        int astride;
        if (r < B_BAS) { Asrc = y + (size_t)node0 * YSTRIDE + r * 128; astride = YSTRIDE; }
        else           { Asrc = xb + (size_t)node0 * D_IN;             astride = D_IN;   }
        #pragma unroll
        for (int i = 0; i < 4; ++i) {
            int flat = i * 256 + t;
            int rw = flat >> 4, c16 = flat & 15;
            int4 v = make_int4(0, 0, 0, 0);
            if (node0 + rw < N_NODES) v = *(const int4*)&Asrc[(size_t)rw * astride + c16 * 8];
            *(int4*)&As[rw * 136 + c16 * 8] = v;
        }
        #pragma unroll
        for (int i = 0; i < 8; ++i) {
            int flat = i * 256 + t;
            int o = flat >> 4, d16 = flat & 15;
            int4 v = *(const int4*)&Wt2[(size_t)o * KTOT + r * 128 + d16 * 8];
            *(int4*)&Bs[o * 136 + d16 * 8] = v;
        }
        __syncthreads();
        #pragma unroll
        for (int ks = 0; ks < 4; ++ks) {
            int kb = ks * 32 + lg * 8;
            bf16x8 af[4];
            #pragma unroll
            for (int mf = 0; mf < 4; ++mf)
                af[mf] = *(const bf16x8*)&As[(mf * 16 + lr) * 136 + kb];
            #pragma unroll
            for (int jn = 0; jn < 2; ++jn) {
                bf16x8 bfr = *(const bf16x8*)&Bs[(w * 32 + jn * 16 + lr) * 136 + kb];
                #pragma unroll
                for (int mf = 0; mf < 4; ++mf)
                    acc[mf][jn] = __builtin_amdgcn_mfma_f32_16x16x32_bf16(af[mf], bfr, acc[mf][jn], 0, 0, 0);
            }
        }
        __syncthreads();
    }

    // epilogue: C/D layout col=lane&15, row=(lane>>4)*4+i  [m89-verified]
    #pragma unroll
    for (int jn = 0; jn < 2; ++jn) {
        int col = w * 32 + jn * 16 + lr;
        float bv = bias[col];
        #pragma unroll
        for (int mf = 0; mf < 4; ++mf) {
            #pragma unroll
            for (int i2 = 0; i2 < 4; ++i2) {
                int row = node0 + mf * 16 + lg * 4 + i2;
                if (row < N_NODES)
                    out[(size_t)row * O_OUT + col] = fmaxf(acc[mf][jn][i2] + bv, 0.f);
            }
        }
    }
}

extern "C" void kernel_launch(void* const* d_in, const int* in_sizes, int n_in,
                              void* d_out, int out_size, void* d_ws, size_t ws_size,
                              hipStream_t stream) {
    (void)in_sizes; (void)n_in; (void)out_size; (void)ws_size;
    const float* x       = (const float*)d_in[0];
    const float* basis_v = (const float*)d_in[1];
    const float* coeffs  = (const float*)d_in[2];
    const float* w_loop  = (const float*)d_in[3];
    const float* bias_p  = (const float*)d_in[4];
    const int*   src     = (const int*)d_in[5];
    const int*   dst     = (const int*)d_in[6];
    const int*   rel     = (const int*)d_in[7];
    float* out = (float*)d_out;

    char* ws = (char*)d_ws;
    unsigned short* Wt2    = (unsigned short*)(ws);             //     163,840 B
    unsigned short* xb     = (unsigned short*)(ws + 163840);    //  12,800,000 B
    int*            deg    = (int*)(ws + 12963840);             //   1,600,000 B
    float*          invf   = (float*)(ws + 14563840);           //   1,600,000 B
    int*            cntd   = (int*)(ws + 16163840);             //     200,000 B
    int*            exoff  = (int*)(ws + 16363840);             //     200,000 B
    int*            offs   = (int*)(ws + 16563840);             //     200,000 B
    int*            cursor = (int*)(ws + 16763840);             //     200,000 B
    int*            bsum   = (int*)(ws + 16963840);             //       1,024 B
    int*            bbase  = (int*)(ws + 16964864);             //       1,024 B
    unsigned*       epack  = (unsigned*)(ws + 16965888);        //   2,400,000 B
    unsigned short* y      = (unsigned short*)(ws + 19365888);  //  51,200,000 B

    hipMemsetAsync(deg, 0, (size_t)NSEG * sizeof(int), stream);

    convert_x_kernel<<<N_NODES * D_IN / 1024, 256, 0, stream>>>(x, xb);
    build_wt2_kernel<<<(O_OUT * KTOT) / 256, 256, 0, stream>>>(basis_v, w_loop, Wt2);
    deg_kernel<<<(E_EDGES + 255) / 256, 256, 0, stream>>>(dst, rel, deg);
    scan1_kernel<<<NB1, 512, 0, stream>>>(deg, cntd, invf, exoff, bsum);
    scan2_kernel<<<1, 128, 0, stream>>>(bsum, bbase);
    scan3_kernel<<<NB1, 512, 0, stream>>>(exoff, bbase, offs, cursor);
    fill_kernel<<<(E_EDGES + 255) / 256, 256, 0, stream>>>(src, dst, rel, cursor, epack);
    segagg_kernel<<<N_NODES / 16, 256, 0, stream>>>(xb, offs, cntd, invf, epack, coeffs, y);
    gemm2_kernel<<<(N_NODES + BM - 1) / BM, 256, 0, stream>>>(y, xb, Wt2, bias_p, out);
}

// Round 8
// 155.002 us; speedup vs baseline: 1.6422x; 1.0995x over previous
//
#include <hip/hip_runtime.h>

#define N_NODES 50000
#define E_EDGES 600000
#define D_IN 128
#define O_OUT 128
#define R_REL 8
#define B_BAS 4
#define KTOT 640                  // 4 basis * 128 + self-loop 128
#define NSEG (N_NODES * R_REL)    // per-(dst,rel) degree table
#define NB1 98                    // ceil(50000/512)
#define YSTRIDE 512               // y row: 4 basis * 128
#define BM 64                     // nodes per gemm block

// prep kernel block ranges
#define NB_CONV 6250              // N*D/1024
#define NB_WT 320                 // 128*640/256
#define NB_DEG 2344               // ceil(E/256)

typedef __attribute__((ext_vector_type(8))) short bf16x8;
typedef __attribute__((ext_vector_type(4))) float f32x4;

static __device__ __forceinline__ unsigned short f2bf(float f) {
    unsigned int u = __float_as_uint(f);
    unsigned int r = (u + 0x7fffu + ((u >> 16) & 1u)) >> 16;
    return (unsigned short)r;
}
static __device__ __forceinline__ float bf2f(unsigned short b) {
    return __uint_as_float(((unsigned int)b) << 16);
}

// Fused: x->bf16 convert | Wt2 build | per-(dst,rel) degree count
__global__ __launch_bounds__(256) void prep_kernel(const float* __restrict__ x,
                                                   unsigned short* __restrict__ xb,
                                                   const float* __restrict__ basis_v,
                                                   const float* __restrict__ w_loop,
                                                   unsigned short* __restrict__ Wt2,
                                                   const int* __restrict__ dst,
                                                   const int* __restrict__ rel,
                                                   int* __restrict__ deg) {
    int b = blockIdx.x;
    if (b < NB_CONV) {
        int i = (b * 256 + threadIdx.x) * 4;
        float4 v = *(const float4*)&x[i];
        ushort4 o;
        o.x = f2bf(v.x); o.y = f2bf(v.y); o.z = f2bf(v.z); o.w = f2bf(v.w);
        *(ushort4*)&xb[i] = o;
    } else if (b < NB_CONV + NB_WT) {
        int i = (b - NB_CONV) * 256 + threadIdx.x;  // over 128*640
        int o = i / KTOT, j = i - o * KTOT;
        int bb = j >> 7, d = j & 127;
        float v = (bb < B_BAS) ? basis_v[((size_t)bb * D_IN + d) * O_OUT + o]
                               : w_loop[d * O_OUT + o];
        Wt2[i] = f2bf(v);
    } else {
        int e = (b - NB_CONV - NB_WT) * 256 + threadIdx.x;
        if (e < E_EDGES) atomicAdd(&deg[dst[e] * R_REL + rel[e]], 1);
    }
}

// Per-dst total count + block-local exclusive scan; emits invf, cursor(=exoff) too
__global__ __launch_bounds__(512) void scan1_kernel(const int* __restrict__ deg,
                                                    int* __restrict__ cntd,
                                                    float* __restrict__ invf,
                                                    int* __restrict__ exoff,
                                                    int* __restrict__ cursor,
                                                    int* __restrict__ bsum) {
    __shared__ int s[512];
    int t = threadIdx.x, i = blockIdx.x * 512 + t;
    int c = 0;
    if (i < N_NODES) {
        #pragma unroll
        for (int r = 0; r < R_REL; ++r) {
            int dg = deg[i * R_REL + r];
            c += dg;
            invf[i * R_REL + r] = 1.0f / (float)max(dg, 1);
        }
        cntd[i] = c;
    }
    s[t] = c;
    __syncthreads();
    #pragma unroll
    for (int off = 1; off < 512; off <<= 1) {
        int add = (t >= off) ? s[t - off] : 0;
        __syncthreads();
        s[t] += add;
        __syncthreads();
    }
    if (i < N_NODES) {
        int v = s[t] - c;
        exoff[i] = v;
        cursor[i] = v;
    }
    if (t == 511) bsum[blockIdx.x] = s[511];
}

__global__ __launch_bounds__(128) void scan2_kernel(const int* __restrict__ bsum,
                                                    int* __restrict__ bbase) {
    __shared__ int s[128];
    int t = threadIdx.x;
    int c = (t < NB1) ? bsum[t] : 0;
    s[t] = c;
    __syncthreads();
    #pragma unroll
    for (int off = 1; off < 128; off <<= 1) {
        int add = (t >= off) ? s[t - off] : 0;
        __syncthreads();
        s[t] += add;
        __syncthreads();
    }
    if (t < NB1) bbase[t] = s[t] - c;
}

// Bucket edges per dst; global slot = blockLocalAtomic + bbase[dstBlock]
__global__ void fill_kernel(const int* __restrict__ src, const int* __restrict__ dst,
                            const int* __restrict__ rel, int* __restrict__ cursor,
                            const int* __restrict__ bbase, unsigned* __restrict__ epack) {
    int e = blockIdx.x * 256 + threadIdx.x;
    if (e >= E_EDGES) return;
    int d = dst[e];
    int pos = atomicAdd(&cursor[d], 1) + bbase[d >> 9];
    epack[pos] = (unsigned)src[e] | ((unsigned)rel[e] << 16);
}

// segagg: one 16-lane group per dst node; 2-deep pipelined edge walk.
// y[d][b*128+..] = sum_edges coeffs[rel,b]*inv_deg*x_src
__global__ __launch_bounds__(256) void segagg_kernel(const unsigned short* __restrict__ xb,
                                                     const int* __restrict__ exoff,
                                                     const int* __restrict__ bbase,
                                                     const int* __restrict__ cntd,
                                                     const float* __restrict__ invf,
                                                     const unsigned* __restrict__ epack,
                                                     const float* __restrict__ coeffs,
                                                     unsigned short* __restrict__ y) {
    int d = blockIdx.x * 16 + (threadIdx.x >> 4);  // grid exact: 50000/16
    int l = threadIdx.x & 15;
    int beg = exoff[d] + bbase[d >> 9];
    int n = cntd[d];
    const unsigned* ep = epack + beg;
    float a0[8] = {}, a1[8] = {}, a2[8] = {}, a3[8] = {};
    int k = 0;
    for (; k + 2 <= n; k += 2) {
        unsigned p0 = ep[k], p1 = ep[k + 1];
        int s0 = p0 & 0xffffu, r0 = p0 >> 16;
        int s1 = p1 & 0xffffu, r1 = p1 >> 16;
        bf16x8 v0 = *(const bf16x8*)&xb[(size_t)s0 * D_IN + l * 8];
        bf16x8 v1 = *(const bf16x8*)&xb[(size_t)s1 * D_IN + l * 8];
        float i0 = invf[d * R_REL + r0];
        float i1 = invf[d * R_REL + r1];
        float4 cA = *(const float4*)&coeffs[r0 * B_BAS];
        float4 cB = *(const float4*)&coeffs[r1 * B_BAS];
        cA.x *= i0; cA.y *= i0; cA.z *= i0; cA.w *= i0;
        cB.x *= i1; cB.y *= i1; cB.z *= i1; cB.w *= i1;
        #pragma unroll
        for (int j = 0; j < 8; ++j) {
            float x0 = bf2f((unsigned short)v0[j]);
            float x1 = bf2f((unsigned short)v1[j]);
            a0[j] += cA.x * x0; a1[j] += cA.y * x0;
            a2[j] += cA.z * x0; a3[j] += cA.w * x0;
            a0[j] += cB.x * x1; a1[j] += cB.y * x1;
            a2[j] += cB.z * x1; a3[j] += cB.w * x1;
        }
    }
    if (k < n) {
        unsigned p0 = ep[k];
        int s0 = p0 & 0xffffu, r0 = p0 >> 16;
        bf16x8 v0 = *(const bf16x8*)&xb[(size_t)s0 * D_IN + l * 8];
        float i0 = invf[d * R_REL + r0];
        float4 cA = *(const float4*)&coeffs[r0 * B_BAS];
        cA.x *= i0; cA.y *= i0; cA.z *= i0; cA.w *= i0;
        #pragma unroll
        for (int j = 0; j < 8; ++j) {
            float x0 = bf2f((unsigned short)v0[j]);
            a0[j] += cA.x * x0; a1[j] += cA.y * x0;
            a2[j] += cA.z * x0; a3[j] += cA.w * x0;
        }
    }
    size_t base = (size_t)d * YSTRIDE + l * 8;
    #pragma unroll
    for (int b = 0; b < 4; ++b) {
        const float* ab = (b == 0) ? a0 : (b == 1) ? a1 : (b == 2) ? a2 : a3;
        ushort4 o0, o1;
        o0.x = f2bf(ab[0]); o0.y = f2bf(ab[1]); o0.z = f2bf(ab[2]); o0.w = f2bf(ab[3]);
        o1.x = f2bf(ab[4]); o1.y = f2bf(ab[5]); o1.z = f2bf(ab[6]); o1.w = f2bf(ab[7]);
        *(ushort4*)&y[base + b * 128] = o0;
        *(ushort4*)&y[base + b * 128 + 4] = o1;
    }
}

// gemm2: out = relu([y | xb] @ [Vstack; w_loop] + bias), K=640.
// A staged in LDS; B fragments read directly from L2-resident Wt2 (160 KB).
__global__ __launch_bounds__(256) void gemm2_kernel(const unsigned short* __restrict__ y,
                                                    const unsigned short* __restrict__ xb,
                                                    const unsigned short* __restrict__ Wt2,
                                                    const float* __restrict__ bias,
                                                    float* __restrict__ out) {
    __shared__ short As[BM * 136];    // 64 rows x 128 k (17.4 KB)
    const int node0 = blockIdx.x * BM;
    const int t = threadIdx.x;
    const int w = t >> 6, l = t & 63;
    const int lr = l & 15, lg = l >> 4;
    const int brow = w * 32;

    f32x4 acc[4][2] = {};

    for (int r = 0; r < 5; ++r) {
        const unsigned short* Asrc;
        int astride;
        if (r < B_BAS) { Asrc = y + (size_t)node0 * YSTRIDE + r * 128; astride = YSTRIDE; }
        else           { Asrc = xb + (size_t)node0 * D_IN;             astride = D_IN;   }
        #pragma unroll
        for (int i = 0; i < 4; ++i) {
            int flat = i * 256 + t;
            int rw = flat >> 4, c16 = flat & 15;
            int4 v = make_int4(0, 0, 0, 0);
            if (node0 + rw < N_NODES) v = *(const int4*)&Asrc[(size_t)rw * astride + c16 * 8];
            *(int4*)&As[rw * 136 + c16 * 8] = v;
        }
        __syncthreads();
        #pragma unroll
        for (int ks = 0; ks < 4; ++ks) {
            int kb = ks * 32 + lg * 8;
            bf16x8 af[4];
            #pragma unroll
            for (int mf = 0; mf < 4; ++mf)
                af[mf] = *(const bf16x8*)&As[(mf * 16 + lr) * 136 + kb];
            #pragma unroll
            for (int jn = 0; jn < 2; ++jn) {
                bf16x8 bfr = *(const bf16x8*)&Wt2[(size_t)(brow + jn * 16 + lr) * KTOT + r * 128 + kb];
                #pragma unroll
                for (int mf = 0; mf < 4; ++mf)
                    acc[mf][jn] = __builtin_amdgcn_mfma_f32_16x16x32_bf16(af[mf], bfr, acc[mf][jn], 0, 0, 0);
            }
        }
        __syncthreads();
    }

    // epilogue: C/D layout col=lane&15, row=(lane>>4)*4+i  [m89-verified]
    #pragma unroll
    for (int jn = 0; jn < 2; ++jn) {
        int col = brow + jn * 16 + lr;
        float bv = bias[col];
        #pragma unroll
        for (int mf = 0; mf < 4; ++mf) {
            #pragma unroll
            for (int i2 = 0; i2 < 4; ++i2) {
                int row = node0 + mf * 16 + lg * 4 + i2;
                if (row < N_NODES)
                    out[(size_t)row * O_OUT + col] = fmaxf(acc[mf][jn][i2] + bv, 0.f);
            }
        }
    }
}

extern "C" void kernel_launch(void* const* d_in, const int* in_sizes, int n_in,
                              void* d_out, int out_size, void* d_ws, size_t ws_size,
                              hipStream_t stream) {
    (void)in_sizes; (void)n_in; (void)out_size; (void)ws_size;
    const float* x       = (const float*)d_in[0];
    const float* basis_v = (const float*)d_in[1];
    const float* coeffs  = (const float*)d_in[2];
    const float* w_loop  = (const float*)d_in[3];
    const float* bias_p  = (const float*)d_in[4];
    const int*   src     = (const int*)d_in[5];
    const int*   dst     = (const int*)d_in[6];
    const int*   rel     = (const int*)d_in[7];
    float* out = (float*)d_out;

    char* ws = (char*)d_ws;
    unsigned short* Wt2    = (unsigned short*)(ws);             //     163,840 B
    unsigned short* xb     = (unsigned short*)(ws + 163840);    //  12,800,000 B
    int*            deg    = (int*)(ws + 12963840);             //   1,600,000 B
    float*          invf   = (float*)(ws + 14563840);           //   1,600,000 B
    int*            cntd   = (int*)(ws + 16163840);             //     200,000 B
    int*            exoff  = (int*)(ws + 16363840);             //     200,000 B
    int*            cursor = (int*)(ws + 16563840);             //     200,000 B
    int*            bsum   = (int*)(ws + 16763840);             //       1,024 B
    int*            bbase  = (int*)(ws + 16764864);             //       1,024 B
    unsigned*       epack  = (unsigned*)(ws + 16765888);        //   2,400,000 B
    unsigned short* y      = (unsigned short*)(ws + 19165888);  //  51,200,000 B

    hipMemsetAsync(deg, 0, (size_t)NSEG * sizeof(int), stream);

    prep_kernel<<<NB_CONV + NB_WT + NB_DEG, 256, 0, stream>>>(x, xb, basis_v, w_loop, Wt2,
                                                              dst, rel, deg);
    scan1_kernel<<<NB1, 512, 0, stream>>>(deg, cntd, invf, exoff, cursor, bsum);
    scan2_kernel<<<1, 128, 0, stream>>>(bsum, bbase);
    fill_kernel<<<NB_DEG, 256, 0, stream>>>(src, dst, rel, cursor, bbase, epack);
    segagg_kernel<<<N_NODES / 16, 256, 0, stream>>>(xb, exoff, bbase, cntd, invf, epack,
                                                    coeffs, y);
    gemm2_kernel<<<(N_NODES + BM - 1) / BM, 256, 0, stream>>>(y, xb, Wt2, bias_p, out);
}

// Round 9
// 138.851 us; speedup vs baseline: 1.8333x; 1.1163x over previous
//
#include <hip/hip_runtime.h>

#define N_NODES 50000
#define E_EDGES 600000
#define D_IN 128
#define O_OUT 128
#define R_REL 8
#define B_BAS 4
#define KTOT 640                  // 4 basis * 128 + self-loop 128
#define NSEG (N_NODES * R_REL)
#define NB1 98                    // ceil(50000/512): scan blocks == coarse buckets
#define YSTRIDE 512               // y row: 4 basis * 128
#define BM 64                     // nodes per gemm block

// prep kernel block ranges
#define NB_CONV 6250              // N*D/1024
#define NB_WT 320                 // 128*640/256
#define NB_DEG 2344               // ceil(E/256)

// binning
#define CHUNK_A 2048
#define NBA 293                   // ceil(600000/2048)

typedef __attribute__((ext_vector_type(8))) short bf16x8;
typedef __attribute__((ext_vector_type(4))) short bf16x4;
typedef __attribute__((ext_vector_type(4))) float f32x4;

static __device__ __forceinline__ unsigned short f2bf(float f) {
    unsigned int u = __float_as_uint(f);
    unsigned int r = (u + 0x7fffu + ((u >> 16) & 1u)) >> 16;
    return (unsigned short)r;
}
static __device__ __forceinline__ float bf2f(unsigned short b) {
    return __uint_as_float(((unsigned int)b) << 16);
}

// Fused: x->bf16 convert | Wt2 build | per-(dst,rel) degree count
__global__ __launch_bounds__(256) void prep_kernel(const float* __restrict__ x,
                                                   unsigned short* __restrict__ xb,
                                                   const float* __restrict__ basis_v,
                                                   const float* __restrict__ w_loop,
                                                   unsigned short* __restrict__ Wt2,
                                                   const int* __restrict__ dst,
                                                   const int* __restrict__ rel,
                                                   int* __restrict__ deg) {
    int b = blockIdx.x;
    if (b < NB_CONV) {
        int i = (b * 256 + threadIdx.x) * 4;
        float4 v = *(const float4*)&x[i];
        ushort4 o;
        o.x = f2bf(v.x); o.y = f2bf(v.y); o.z = f2bf(v.z); o.w = f2bf(v.w);
        *(ushort4*)&xb[i] = o;
    } else if (b < NB_CONV + NB_WT) {
        int i = (b - NB_CONV) * 256 + threadIdx.x;  // over 128*640
        int o = i / KTOT, j = i - o * KTOT;
        int bb = j >> 7, d = j & 127;
        float v = (bb < B_BAS) ? basis_v[((size_t)bb * D_IN + d) * O_OUT + o]
                               : w_loop[d * O_OUT + o];
        Wt2[i] = f2bf(v);
    } else {
        int e = (b - NB_CONV - NB_WT) * 256 + threadIdx.x;
        if (e < E_EDGES) atomicAdd(&deg[dst[e] * R_REL + rel[e]], 1);
    }
}

// Per-dst total count + block-local exclusive scan; emits invf too
__global__ __launch_bounds__(512) void scan1_kernel(const int* __restrict__ deg,
                                                    int* __restrict__ cntd,
                                                    float* __restrict__ invf,
                                                    int* __restrict__ exoff,
                                                    int* __restrict__ bsum) {
    __shared__ int s[512];
    int t = threadIdx.x, i = blockIdx.x * 512 + t;
    int c = 0;
    if (i < N_NODES) {
        #pragma unroll
        for (int r = 0; r < R_REL; ++r) {
            int dg = deg[i * R_REL + r];
            c += dg;
            invf[i * R_REL + r] = 1.0f / (float)max(dg, 1);
        }
        cntd[i] = c;
    }
    s[t] = c;
    __syncthreads();
    #pragma unroll
    for (int off = 1; off < 512; off <<= 1) {
        int add = (t >= off) ? s[t - off] : 0;
        __syncthreads();
        s[t] += add;
        __syncthreads();
    }
    if (i < N_NODES) exoff[i] = s[t] - c;
    if (t == 511) bsum[blockIdx.x] = s[511];
}

// Scan 98 block sums -> bbase[0..98] (with total at [98]); init cursor98 copy
__global__ __launch_bounds__(128) void scan2_kernel(const int* __restrict__ bsum,
                                                    int* __restrict__ bbase,
                                                    int* __restrict__ cursor98) {
    __shared__ int s[128];
    int t = threadIdx.x;
    int c = (t < NB1) ? bsum[t] : 0;
    s[t] = c;
    __syncthreads();
    #pragma unroll
    for (int off = 1; off < 128; off <<= 1) {
        int add = (t >= off) ? s[t - off] : 0;
        __syncthreads();
        s[t] += add;
        __syncthreads();
    }
    if (t < NB1) {
        int v = s[t] - c;
        bbase[t] = v;
        cursor98[t] = v;
    }
    if (t == NB1 - 1) bbase[NB1] = s[t];
}

// Pass A: bin edges into 98 coarse buckets (512 dsts each), block-contiguous runs.
// coarse payload: src(16) | rel(3)<<16 | dlow(9)<<19
__global__ __launch_bounds__(256) void binA_kernel(const int* __restrict__ src,
                                                   const int* __restrict__ dst,
                                                   const int* __restrict__ rel,
                                                   int* __restrict__ cursor98,
                                                   unsigned* __restrict__ coarse) {
    __shared__ int hist[NB1];
    __shared__ int base[NB1];
    int t = threadIdx.x;
    if (t < NB1) hist[t] = 0;
    __syncthreads();
    int e0 = blockIdx.x * CHUNK_A;
    for (int i = t; i < CHUNK_A; i += 256) {
        int e = e0 + i;
        if (e < E_EDGES) atomicAdd(&hist[dst[e] >> 9], 1);
    }
    __syncthreads();
    if (t < NB1) {
        int h = hist[t];
        base[t] = h ? atomicAdd(&cursor98[t], h) : 0;
        hist[t] = 0;
    }
    __syncthreads();
    for (int i = t; i < CHUNK_A; i += 256) {
        int e = e0 + i;
        if (e < E_EDGES) {
            int d = dst[e], b = d >> 9;
            int pos = base[b] + atomicAdd(&hist[b], 1);
            coarse[pos] = (unsigned)src[e] | ((unsigned)rel[e] << 16)
                        | ((unsigned)(d & 511) << 19);
        }
    }
}

// Pass B: one block per coarse bucket; exact per-dst slots via LDS counters.
// All writes land within the bucket's ~24 KB epack window (L2-merged).
__global__ __launch_bounds__(512) void binB_kernel(const unsigned* __restrict__ coarse,
                                                   const int* __restrict__ bbase,
                                                   const int* __restrict__ exoff,
                                                   unsigned* __restrict__ epack) {
    __shared__ int lcnt[512];
    int b = blockIdx.x, t = threadIdx.x;
    int d0 = b << 9;
    lcnt[t] = (d0 + t < N_NODES) ? exoff[d0 + t] : 0;
    __syncthreads();
    int s0 = bbase[b], s1 = bbase[b + 1];
    for (int i = s0 + t; i < s1; i += 512) {
        unsigned p = coarse[i];
        int dlow = (p >> 19) & 511;
        int pos = s0 + atomicAdd(&lcnt[dlow], 1);
        epack[pos] = p & 0x7ffffu;  // src | rel<<16
    }
}

// segagg: 32 lanes per dst node; 2-deep pipelined edge walk.
// y[d][b*128+..] = sum_edges coeffs[rel,b]*inv_deg*x_src
__global__ __launch_bounds__(256) void segagg_kernel(const unsigned short* __restrict__ xb,
                                                     const int* __restrict__ exoff,
                                                     const int* __restrict__ bbase,
                                                     const int* __restrict__ cntd,
                                                     const float* __restrict__ invf,
                                                     const unsigned* __restrict__ epack,
                                                     const float* __restrict__ coeffs,
                                                     unsigned short* __restrict__ y) {
    int d = blockIdx.x * 8 + (threadIdx.x >> 5);  // grid exact: 50000/8
    int l = threadIdx.x & 31;
    int beg = exoff[d] + bbase[d >> 9];
    int n = cntd[d];
    const unsigned* ep = epack + beg;
    float a0[4] = {}, a1[4] = {}, a2[4] = {}, a3[4] = {};
    int k = 0;
    for (; k + 2 <= n; k += 2) {
        unsigned p0 = ep[k], p1 = ep[k + 1];
        int s0 = p0 & 0xffffu, r0 = p0 >> 16;
        int s1 = p1 & 0xffffu, r1 = p1 >> 16;
        bf16x4 v0 = *(const bf16x4*)&xb[(size_t)s0 * D_IN + l * 4];
        bf16x4 v1 = *(const bf16x4*)&xb[(size_t)s1 * D_IN + l * 4];
        float i0 = invf[d * R_REL + r0];
        float i1 = invf[d * R_REL + r1];
        float4 cA = *(const float4*)&coeffs[r0 * B_BAS];
        float4 cB = *(const float4*)&coeffs[r1 * B_BAS];
        cA.x *= i0; cA.y *= i0; cA.z *= i0; cA.w *= i0;
        cB.x *= i1; cB.y *= i1; cB.z *= i1; cB.w *= i1;
        #pragma unroll
        for (int j = 0; j < 4; ++j) {
            float x0 = bf2f((unsigned short)v0[j]);
            float x1 = bf2f((unsigned short)v1[j]);
            a0[j] += cA.x * x0; a1[j] += cA.y * x0;
            a2[j] += cA.z * x0; a3[j] += cA.w * x0;
            a0[j] += cB.x * x1; a1[j] += cB.y * x1;
            a2[j] += cB.z * x1; a3[j] += cB.w * x1;
        }
    }
    if (k < n) {
        unsigned p0 = ep[k];
        int s0 = p0 & 0xffffu, r0 = p0 >> 16;
        bf16x4 v0 = *(const bf16x4*)&xb[(size_t)s0 * D_IN + l * 4];
        float i0 = invf[d * R_REL + r0];
        float4 cA = *(const float4*)&coeffs[r0 * B_BAS];
        cA.x *= i0; cA.y *= i0; cA.z *= i0; cA.w *= i0;
        #pragma unroll
        for (int j = 0; j < 4; ++j) {
            float x0 = bf2f((unsigned short)v0[j]);
            a0[j] += cA.x * x0; a1[j] += cA.y * x0;
            a2[j] += cA.z * x0; a3[j] += cA.w * x0;
        }
    }
    size_t base = (size_t)d * YSTRIDE + l * 4;
    #pragma unroll
    for (int b = 0; b < 4; ++b) {
        const float* ab = (b == 0) ? a0 : (b == 1) ? a1 : (b == 2) ? a2 : a3;
        ushort4 o;
        o.x = f2bf(ab[0]); o.y = f2bf(ab[1]); o.z = f2bf(ab[2]); o.w = f2bf(ab[3]);
        *(ushort4*)&y[base + b * 128] = o;
    }
}

// gemm2: out = relu([y | xb] @ [Vstack; w_loop] + bias), K=640.
// A staged in LDS; B fragments read directly from L2-resident Wt2 (160 KB).
__global__ __launch_bounds__(256) void gemm2_kernel(const unsigned short* __restrict__ y,
                                                    const unsigned short* __restrict__ xb,
                                                    const unsigned short* __restrict__ Wt2,
                                                    const float* __restrict__ bias,
                                                    float* __restrict__ out) {
    __shared__ short As[BM * 136];    // 64 rows x 128 k (17.4 KB)
    const int node0 = blockIdx.x * BM;
    const int t = threadIdx.x;
    const int w = t >> 6, l = t & 63;
    const int lr = l & 15, lg = l >> 4;
    const int brow = w * 32;

    f32x4 acc[4][2] = {};

    for (int r = 0; r < 5; ++r) {
        const unsigned short* Asrc;
        int astride;
        if (r < B_BAS) { Asrc = y + (size_t)node0 * YSTRIDE + r * 128; astride = YSTRIDE; }
        else           { Asrc = xb + (size_t)node0 * D_IN;             astride = D_IN;   }
        #pragma unroll
        for (int i = 0; i < 4; ++i) {
            int flat = i * 256 + t;
            int rw = flat >> 4, c16 = flat & 15;
            int4 v = make_int4(0, 0, 0, 0);
            if (node0 + rw < N_NODES) v = *(const int4*)&Asrc[(size_t)rw * astride + c16 * 8];
            *(int4*)&As[rw * 136 + c16 * 8] = v;
        }
        __syncthreads();
        #pragma unroll
        for (int ks = 0; ks < 4; ++ks) {
            int kb = ks * 32 + lg * 8;
            bf16x8 af[4];
            #pragma unroll
            for (int mf = 0; mf < 4; ++mf)
                af[mf] = *(const bf16x8*)&As[(mf * 16 + lr) * 136 + kb];
            #pragma unroll
            for (int jn = 0; jn < 2; ++jn) {
                bf16x8 bfr = *(const bf16x8*)&Wt2[(size_t)(brow + jn * 16 + lr) * KTOT + r * 128 + kb];
                #pragma unroll
                for (int mf = 0; mf < 4; ++mf)
                    acc[mf][jn] = __builtin_amdgcn_mfma_f32_16x16x32_bf16(af[mf], bfr, acc[mf][jn], 0, 0, 0);
            }
        }
        __syncthreads();
    }

    // epilogue: C/D layout col=lane&15, row=(lane>>4)*4+i  [m89-verified]
    #pragma unroll
    for (int jn = 0; jn < 2; ++jn) {
        int col = brow + jn * 16 + lr;
        float bv = bias[col];
        #pragma unroll
        for (int mf = 0; mf < 4; ++mf) {
            #pragma unroll
            for (int i2 = 0; i2 < 4; ++i2) {
                int row = node0 + mf * 16 + lg * 4 + i2;
                if (row < N_NODES)
                    out[(size_t)row * O_OUT + col] = fmaxf(acc[mf][jn][i2] + bv, 0.f);
            }
        }
    }
}

extern "C" void kernel_launch(void* const* d_in, const int* in_sizes, int n_in,
                              void* d_out, int out_size, void* d_ws, size_t ws_size,
                              hipStream_t stream) {
    (void)in_sizes; (void)n_in; (void)out_size; (void)ws_size;
    const float* x       = (const float*)d_in[0];
    const float* basis_v = (const float*)d_in[1];
    const float* coeffs  = (const float*)d_in[2];
    const float* w_loop  = (const float*)d_in[3];
    const float* bias_p  = (const float*)d_in[4];
    const int*   src     = (const int*)d_in[5];
    const int*   dst     = (const int*)d_in[6];
    const int*   rel     = (const int*)d_in[7];
    float* out = (float*)d_out;

    char* ws = (char*)d_ws;
    unsigned short* Wt2      = (unsigned short*)(ws);             //     163,840 B
    unsigned short* xb       = (unsigned short*)(ws + 163840);    //  12,800,000 B
    int*            deg      = (int*)(ws + 12963840);             //   1,600,000 B
    float*          invf     = (float*)(ws + 14563840);           //   1,600,000 B
    int*            cntd     = (int*)(ws + 16163840);             //     200,000 B
    int*            exoff    = (int*)(ws + 16363840);             //     200,000 B
    int*            bsum     = (int*)(ws + 16563840);             //       1,024 B
    int*            bbase    = (int*)(ws + 16564864);             //       1,024 B (99 ints)
    int*            cursor98 = (int*)(ws + 16565888);             //       1,024 B
    unsigned*       coarse   = (unsigned*)(ws + 16566912);        //   2,400,000 B
    unsigned*       epack    = (unsigned*)(ws + 18966912);        //   2,400,000 B
    unsigned short* y        = (unsigned short*)(ws + 21366912);  //  51,200,000 B

    hipMemsetAsync(deg, 0, (size_t)NSEG * sizeof(int), stream);

    prep_kernel<<<NB_CONV + NB_WT + NB_DEG, 256, 0, stream>>>(x, xb, basis_v, w_loop, Wt2,
                                                              dst, rel, deg);
    scan1_kernel<<<NB1, 512, 0, stream>>>(deg, cntd, invf, exoff, bsum);
    scan2_kernel<<<1, 128, 0, stream>>>(bsum, bbase, cursor98);
    binA_kernel<<<NBA, 256, 0, stream>>>(src, dst, rel, cursor98, coarse);
    binB_kernel<<<NB1, 512, 0, stream>>>(coarse, bbase, exoff, epack);
    segagg_kernel<<<N_NODES / 8, 256, 0, stream>>>(xb, exoff, bbase, cntd, invf, epack,
                                                   coeffs, y);
    gemm2_kernel<<<(N_NODES + BM - 1) / BM, 256, 0, stream>>>(y, xb, Wt2, bias_p, out);
}